// Round 11
// baseline (210.226 us; speedup 1.0000x reference)
//
#include <hip/hip_runtime.h>
#include <math.h>

#define N_NODES 10000
#define N_EDGES 640000
#define ELLW    192     // max in-degree slots; Poisson(64) max ~110, P[>192]~1e-19

#define CHUNKS  128
#define CHUNK_E 5000    // N_EDGES / CHUNKS exactly
#define GB      625     // ceil(10000/16) gemm1 tiles (TM=16)
#define PB      (CHUNKS + GB)   // 753 blocks; 40KB LDS -> 4 blk/CU -> capacity 1024 >= 753
                                // => all blocks co-resident: partial-grid spin-wait is safe
#define MAGIC   0x9E3779B97F4A7C15ULL

typedef unsigned long long ull;
typedef unsigned int uint;
typedef unsigned short ushort;
typedef unsigned char uchar;

#define FIXED_SCALE 262144.0f   // 2^18; count<<24 | fixed18(sum_w); max cnt<64 -> no carry

// ---------------- workspace layout (bytes) ----------------
// xw1b     : N*128 bf16   @ 0            (2,560,000)
// xw2b     : N*64  bf16   @  5,120,000   (1,280,000)
// epack    : N*ELLW ull   @  6,400,000   (15,360,000)  (nrm_bits<<32 | src)
// blockcnt : CHUNKS*N u32 @ 21,760,000   (5,120,000)   [also epack-overshoot landing zone]
// base8    : CHUNKS*N u8  @ 26,880,000   (1,280,000)
// sd32     : E u32        @ 28,800,000   (2,560,000)   (rank4|dst14|src14)
// cnt_arr  : N int        @ 31,360,000   (40,000)
// dinv     : N f32        @ 31,400,000   (40,000)
// w2pg     : 4096 u32     @ 31,440,000   (16,384)      W2 packed bf16x2
// histFlag : 128 ull      @ 31,456,384   (1,024)       MAGIC when chunk hist done
// scanFlag : 40 ull       @ 31,457,408   (320)         MAGIC when scan block done
// (harness re-poisons the full workspace every iteration -> stale MAGICs cleared)

__device__ __forceinline__ float bf_lo(uint u) { return __uint_as_float(u << 16); }
__device__ __forceinline__ float bf_hi(uint u) { return __uint_as_float(u & 0xffff0000u); }
__device__ __forceinline__ ushort f2bf(float v) {
    uint u = __float_as_uint(v);
    uint r = u + 0x7fffu + ((u >> 16) & 1u);   // round-to-nearest-even
    return (ushort)(r >> 16);
}

// 8 FMAs: one edge's 4 packed uints (8 bf16 cols) into acc[0..7]
#define ACC8(n, r) \
    acc[0] = fmaf(n, bf_lo((r).x), acc[0]); acc[1] = fmaf(n, bf_hi((r).x), acc[1]); \
    acc[2] = fmaf(n, bf_lo((r).y), acc[2]); acc[3] = fmaf(n, bf_hi((r).y), acc[3]); \
    acc[4] = fmaf(n, bf_lo((r).z), acc[4]); acc[5] = fmaf(n, bf_hi((r).z), acc[5]); \
    acc[6] = fmaf(n, bf_lo((r).w), acc[6]); acc[7] = fmaf(n, bf_hi((r).w), acc[7]);

// ====== prepF: fused hist + gemm1 + scan + W2-pack + ELL fill (753 blocks) ======
// Flag-based partial sync (deadlock-free: whole grid co-resident, see PB note).
// R9 lesson: unthrottled spins flood the coherence point (prepF was 135us at
// 5% VALUBusy). s_sleep(8) backoff (~512 cyc/poll) cuts poll traffic ~100x.
__global__ __launch_bounds__(256, 4) void prepF(const int* __restrict__ ei,
                                                const float* __restrict__ ew,
                                                uint* __restrict__ sd32,
                                                uint* __restrict__ blockcnt,
                                                const float* __restrict__ x,
                                                const float* __restrict__ W1,
                                                ushort* __restrict__ xw1b,
                                                uchar* __restrict__ base8,
                                                int* __restrict__ cnt_arr,
                                                float* __restrict__ dinv,
                                                const float* __restrict__ W2,
                                                uint* __restrict__ w2pg,
                                                ull* __restrict__ epack,
                                                ull* histFlag,
                                                ull* scanFlag) {
    __shared__ __align__(16) uint smem[N_NODES];   // 40 KB; gemm overlays sA|sB
    const int tid = threadIdx.x;
    const int b = blockIdx.x;
    if (b < CHUNKS) {
        // ---------------- chunk histogram (chunk = b) ----------------
        const int c = b;
        __shared__ int sflag;
        if (tid == 0) sflag = 0;
        for (int i = tid; i < N_NODES; i += 256) smem[i] = 0u;
        __syncthreads();
        // layout self-detect: int64 LE [2,E] => sampled high dwords all zero
        int a = (tid < 64) ? ei[2 * (c * CHUNK_E + tid) + 1] : 0;
        if (a) atomicOr(&sflag, 1);
        __syncthreads();
        const int f = sflag;                     // 1 => int32 layout
        const ull* ei64 = (const ull*)ei;
        for (int k = tid; k < CHUNK_E; k += 256) {
            int e = c * CHUNK_E + k;
            int s, d;
            if (f) { s = ei[e];        d = ei[N_EDGES + e]; }
            else   { s = (int)ei64[e]; d = (int)ei64[N_EDGES + e]; }
            float w = ew[e];
            uint fx = (uint)(w * FIXED_SCALE + 0.5f);
            uint old = atomicAdd(&smem[d], (1u << 24) | fx);
            uint r = (old >> 24) & 15u;          // per-chunk rank; fits 4 bits
            sd32[e] = (r << 28) | ((uint)d << 14) | (uint)s;
        }
        __syncthreads();
        for (int i = tid; i < N_NODES; i += 256)
            blockcnt[c * N_NODES + i] = smem[i];
        __syncthreads();
        if (tid == 0) {
            __threadfence();                     // device-scope: push sd32/blockcnt past XCD L2
            __hip_atomic_store(&histFlag[c], MAGIC, __ATOMIC_RELEASE,
                               __HIP_MEMORY_SCOPE_AGENT);
        }
        if (b >= 40 && b < 56) {
            // W2 pack (independent): w2pg[k2*64+c] = bf16|bf16<<16
            int i = (b - 40) * 256 + tid;        // 16*256 = 4096 entries
            int k2 = i >> 6, cc = i & 63;
            uint lo = (uint)f2bf(W2[(2 * k2) * 64 + cc]);
            uint hi = (uint)f2bf(W2[(2 * k2 + 1) * 64 + cc]);
            w2pg[i] = lo | (hi << 16);
        }
        if (b < 40) {
            // ---------------- per-node scan (hidden under gemm1) ----------------
            if (tid < CHUNKS)
                while (__hip_atomic_load(&histFlag[tid], __ATOMIC_ACQUIRE,
                                         __HIP_MEMORY_SCOPE_AGENT) != MAGIC)
                    __builtin_amdgcn_s_sleep(8);         // ~512 cyc backoff
            __syncthreads();
            int n = b * 256 + tid;
            if (n < N_NODES) {
                uint wsum = 0;
                int run = 0;
#pragma unroll 8
                for (int c2 = 0; c2 < CHUNKS; ++c2) {
                    uint v = blockcnt[c2 * N_NODES + n];
                    base8[c2 * N_NODES + n] = (uchar)run;
                    run += (int)(v >> 24);
                    wsum += v & 0xffffffu;
                }
                cnt_arr[n] = run;
                float dg = 1.0f + (float)wsum * (1.0f / FIXED_SCALE);
                dinv[n] = (float)(1.0 / sqrt((double)dg));
            }
            __syncthreads();
            if (tid == 0) {
                __threadfence();
                __hip_atomic_store(&scanFlag[b], MAGIC, __ATOMIC_RELEASE,
                                   __HIP_MEMORY_SCOPE_AGENT);
            }
        }
    } else {
        // ---------------- gemm1: xw1b[16-row tile] = x @ W1 ----------------
        constexpr int K = 128, TM = 16, KT = 32, NCOL = 128, RPT = 8, LDA = KT + 4;
        float* sA = (float*)smem;           // [16][36]
        float* sB = sA + TM * LDA;          // [32][128]
        int blk = b - CHUNKS;
        int c = tid % NCOL, rr = tid / NCOL;      // rr in [0,2)
        int row0 = blk * TM;
        float acc[RPT];
#pragma unroll
        for (int r = 0; r < RPT; ++r) acc[r] = 0.0f;
        for (int k0 = 0; k0 < K; k0 += KT) {
            for (int i = tid; i < TM * KT; i += 256) {
                int r = i / KT, k = i % KT;
                int gr = row0 + r;
                sA[r * LDA + k] = (gr < N_NODES) ? x[gr * K + k0 + k] : 0.0f;
            }
            for (int i = tid; i < KT * NCOL; i += 256) {
                int k = i / NCOL, cc = i % NCOL;
                sB[k * NCOL + cc] = W1[(k0 + k) * NCOL + cc];
            }
            __syncthreads();
#pragma unroll
            for (int k = 0; k < KT; k += 4) {
                float b0 = sB[(k + 0) * NCOL + c];
                float b1 = sB[(k + 1) * NCOL + c];
                float b2 = sB[(k + 2) * NCOL + c];
                float b3 = sB[(k + 3) * NCOL + c];
#pragma unroll
                for (int r = 0; r < RPT; ++r) {
                    const float4 av = *(const float4*)&sA[(rr * RPT + r) * LDA + k];
                    acc[r] = fmaf(av.x, b0, acc[r]);
                    acc[r] = fmaf(av.y, b1, acc[r]);
                    acc[r] = fmaf(av.z, b2, acc[r]);
                    acc[r] = fmaf(av.w, b3, acc[r]);
                }
            }
            __syncthreads();
        }
#pragma unroll
        for (int r = 0; r < RPT; ++r) {
            int gr = row0 + rr * RPT + r;
            if (gr < N_NODES) xw1b[gr * NCOL + c] = f2bf(acc[r]);
        }
    }
    // ---------------- all 753 blocks: wait for scan, then ELL fill ----------------
    if (tid < 40)
        while (__hip_atomic_load(&scanFlag[tid], __ATOMIC_ACQUIRE,
                                 __HIP_MEMORY_SCOPE_AGENT) != MAGIC)
            __builtin_amdgcn_s_sleep(8);                 // ~512 cyc backoff
    __syncthreads();
    for (int e = b * 256 + tid; e < N_EDGES; e += PB * 256) {
        uint sd = sd32[e];
        int s = (int)(sd & 0x3fffu);
        int d = (int)((sd >> 14) & 0x3fffu);
        int r = (int)(sd >> 28);
        int c = e / CHUNK_E;
        float nrm = dinv[s] * ew[e] * dinv[d];
        int slot = (int)base8[c * N_NODES + d] + r;
        if (slot < ELLW)
            epack[(long)d * ELLW + slot] = ((ull)__float_as_uint(nrm) << 32) | (ull)(uint)s;
    }
}

// ===== aggC: 2500 blocks x 256, wave per node, quad-gather (R7 best-measured).
// Wave = 4 row-groups x 16 lanes; one dwordx4 gather covers 4 edges (1 KB). =====
__global__ __launch_bounds__(256, 6) void aggC(const ushort* __restrict__ xw1b,
                                               const ull* __restrict__ epack,
                                               const int* __restrict__ cnt_arr,
                                               const float* __restrict__ dinv,
                                               const float* __restrict__ b1,
                                               const uint* __restrict__ w2pg,
                                               ushort* __restrict__ xw2b) {
    __shared__ float hl[4][128];        // 2 KB f32 h rows
    __shared__ uint w2p[64 * 64];       // 16 KB packed bf16x2 W2
    const uint* __restrict__ xw32 = (const uint*)xw1b;   // row = 64 uints
    const int tid = threadIdx.x;
    const int l = tid & 63;
    const int wv = tid >> 6;
    const int g = l >> 4;               // row-group 0..3
    const int q = l & 15;               // covers cols 8q..8q+7 (uints 4q..4q+3)
    const int node = blockIdx.x * 4 + wv;

    int cnt = __builtin_amdgcn_readfirstlane(cnt_arr[node]);
    if (cnt > ELLW) cnt = ELLW;
    const ull* ep = epack + (long)node * ELLW;

    // prologue: edge meta for batch 0 (latency hides under w2p staging)
    ulonglong2 eA = *(const ulonglong2*)(ep + 2 * g);        // edges 2g, 2g+1
    ulonglong2 eB = *(const ulonglong2*)(ep + 8 + 2 * g);    // edges 8+2g, 9+2g

    for (int i = tid; i < 64 * 64; i += 256) w2p[i] = w2pg[i];

    float acc[8];
#pragma unroll
    for (int i = 0; i < 8; ++i) acc[i] = 0.0f;

    for (int j = 0; j < cnt; j += 16) {
        // prefetch next batch's meta (OOB overshoot lands in blockcnt region)
        ulonglong2 nA = *(const ulonglong2*)(ep + j + 16 + 2 * g);
        ulonglong2 nB = *(const ulonglong2*)(ep + j + 24 + 2 * g);
        uint s0 = (uint)eA.x & 0x3fffu;
        uint s1 = (uint)eA.y & 0x3fffu;
        uint s2 = (uint)eB.x & 0x3fffu;
        uint s3 = (uint)eB.y & 0x3fffu;
        uint4 r0 = *(const uint4*)(xw32 + s0 * 64 + q * 4);
        uint4 r1 = *(const uint4*)(xw32 + s1 * 64 + q * 4);
        uint4 r2 = *(const uint4*)(xw32 + s2 * 64 + q * 4);
        uint4 r3 = *(const uint4*)(xw32 + s3 * 64 + q * 4);
        float n0 = (j + 2 * g     < cnt) ? __uint_as_float((uint)(eA.x >> 32)) : 0.0f;
        float n1 = (j + 2 * g + 1 < cnt) ? __uint_as_float((uint)(eA.y >> 32)) : 0.0f;
        float n2 = (j + 2 * g + 8 < cnt) ? __uint_as_float((uint)(eB.x >> 32)) : 0.0f;
        float n3 = (j + 2 * g + 9 < cnt) ? __uint_as_float((uint)(eB.y >> 32)) : 0.0f;
        ACC8(n0, r0)
        ACC8(n1, r1)
        ACC8(n2, r2)
        ACC8(n3, r3)
        eA = nA; eB = nB;
    }

    // merge the 4 row-groups' partials
#pragma unroll
    for (int i = 0; i < 8; ++i) {
        acc[i] += __shfl_xor(acc[i], 16, 64);
        acc[i] += __shfl_xor(acc[i], 32, 64);
    }

    float dn = dinv[node];
    float d2 = dn * dn;
    uint4 sv = *(const uint4*)(xw32 + node * 64 + q * 4);    // self row slice
    float4 b1a = *(const float4*)(b1 + 8 * q);
    float4 b1b = *(const float4*)(b1 + 8 * q + 4);
    if (g == 0) {
        hl[wv][8 * q + 0] = fmaxf(acc[0] + d2 * bf_lo(sv.x) + b1a.x, 0.0f);
        hl[wv][8 * q + 1] = fmaxf(acc[1] + d2 * bf_hi(sv.x) + b1a.y, 0.0f);
        hl[wv][8 * q + 2] = fmaxf(acc[2] + d2 * bf_lo(sv.y) + b1a.z, 0.0f);
        hl[wv][8 * q + 3] = fmaxf(acc[3] + d2 * bf_hi(sv.y) + b1a.w, 0.0f);
        hl[wv][8 * q + 4] = fmaxf(acc[4] + d2 * bf_lo(sv.z) + b1b.x, 0.0f);
        hl[wv][8 * q + 5] = fmaxf(acc[5] + d2 * bf_hi(sv.z) + b1b.y, 0.0f);
        hl[wv][8 * q + 6] = fmaxf(acc[6] + d2 * bf_lo(sv.w) + b1b.z, 0.0f);
        hl[wv][8 * q + 7] = fmaxf(acc[7] + d2 * bf_hi(sv.w) + b1b.w, 0.0f);
    }
    __syncthreads();

    // mini-gemm: thread (wv,l) -> node, column l. hl broadcast reads; one
    // ds_read_b32 per two k's from packed bf16 W2.
    float acc2 = 0.0f;
#pragma unroll 8
    for (int k2 = 0; k2 < 64; ++k2) {
        uint w = w2p[k2 * 64 + l];
        acc2 = fmaf(hl[wv][2 * k2],     bf_lo(w), acc2);
        acc2 = fmaf(hl[wv][2 * k2 + 1], bf_hi(w), acc2);
    }
    xw2b[node * 64 + l] = f2bf(acc2);
}

// ===== agg2: 2500 blocks x 256, wave per node, quad-gather, 2-DEEP prefetch
// (R7 best-measured). No LDS -> launch_bounds(256,8). =====
__global__ __launch_bounds__(256, 8) void agg2(const ushort* __restrict__ xw2b,
                                               const ull* __restrict__ epack,
                                               const int* __restrict__ cnt_arr,
                                               const float* __restrict__ dinv,
                                               const float* __restrict__ b2,
                                               float* __restrict__ out) {
    const uint* __restrict__ xw32 = (const uint*)xw2b;   // row = 32 uints
    const int tid = threadIdx.x;
    const int l = tid & 63;
    const int wv = tid >> 6;
    const int g = l >> 3;               // row-group 0..7
    const int q = l & 7;                // covers cols 8q..8q+7 (uints 4q..4q+3)
    const int node = blockIdx.x * 4 + wv;

    int cnt = __builtin_amdgcn_readfirstlane(cnt_arr[node]);
    if (cnt > ELLW) cnt = ELLW;
    const ull* ep = epack + (long)node * ELLW;

    ulonglong2 eA = *(const ulonglong2*)(ep + 2 * g);        // iter j=0 meta
    ulonglong2 eB = *(const ulonglong2*)(ep + 16 + 2 * g);   // iter j=16 meta

    float acc[8];
#pragma unroll
    for (int i = 0; i < 8; ++i) acc[i] = 0.0f;

    for (int j = 0; j < cnt; j += 16) {
        // prefetch iter j+32's meta (2-deep; OOB overshoot stays in workspace)
        ulonglong2 nA = *(const ulonglong2*)(ep + j + 32 + 2 * g);
        uint s0 = (uint)eA.x & 0x3fffu;
        uint s1 = (uint)eA.y & 0x3fffu;
        uint4 r0 = *(const uint4*)(xw32 + s0 * 32 + q * 4);
        uint4 r1 = *(const uint4*)(xw32 + s1 * 32 + q * 4);
        float n0 = (j + 2 * g     < cnt) ? __uint_as_float((uint)(eA.x >> 32)) : 0.0f;
        float n1 = (j + 2 * g + 1 < cnt) ? __uint_as_float((uint)(eA.y >> 32)) : 0.0f;
        ACC8(n0, r0)
        ACC8(n1, r1)
        eA = eB; eB = nA;
    }

#pragma unroll
    for (int i = 0; i < 8; ++i) {
        acc[i] += __shfl_xor(acc[i], 8, 64);
        acc[i] += __shfl_xor(acc[i], 16, 64);
        acc[i] += __shfl_xor(acc[i], 32, 64);
    }

    float dn = dinv[node];
    float d2 = dn * dn;
    uint4 sv = *(const uint4*)(xw32 + node * 32 + q * 4);    // self row slice
    float4 b2a = *(const float4*)(b2 + 8 * q);
    float4 b2b = *(const float4*)(b2 + 8 * q + 4);
    if (g == 0) {
        float4 oa, ob;
        oa.x = acc[0] + d2 * bf_lo(sv.x) + b2a.x;
        oa.y = acc[1] + d2 * bf_hi(sv.x) + b2a.y;
        oa.z = acc[2] + d2 * bf_lo(sv.y) + b2a.z;
        oa.w = acc[3] + d2 * bf_hi(sv.y) + b2a.w;
        ob.x = acc[4] + d2 * bf_lo(sv.z) + b2b.x;
        ob.y = acc[5] + d2 * bf_hi(sv.z) + b2b.y;
        ob.z = acc[6] + d2 * bf_lo(sv.w) + b2b.z;
        ob.w = acc[7] + d2 * bf_hi(sv.w) + b2b.w;
        *(float4*)(out + node * 64 + 8 * q)     = oa;
        *(float4*)(out + node * 64 + 8 * q + 4) = ob;
    }
}

extern "C" void kernel_launch(void* const* d_in, const int* in_sizes, int n_in,
                              void* d_out, int out_size, void* d_ws, size_t ws_size,
                              hipStream_t stream) {
    const float* x  = (const float*)d_in[0];
    const int*   ei = (const int*)d_in[1];
    const float* ew = (const float*)d_in[2];
    const float* W1 = (const float*)d_in[3];
    const float* b1 = (const float*)d_in[4];
    const float* W2 = (const float*)d_in[5];
    const float* b2 = (const float*)d_in[6];
    float* out = (float*)d_out;

    char* ws = (char*)d_ws;
    ushort* xw1b    = (ushort*)(ws + 0);
    ushort* xw2b    = (ushort*)(ws + 5120000);
    ull*    epack   = (ull*)   (ws + 6400000);
    uint*   blockcnt= (uint*)  (ws + 21760000);
    uchar*  base8   = (uchar*) (ws + 26880000);
    uint*   sd32    = (uint*)  (ws + 28800000);
    int*    cnt_arr = (int*)   (ws + 31360000);
    float*  dinv    = (float*) (ws + 31400000);
    uint*   w2pg    = (uint*)  (ws + 31440000);
    ull*    histFlag= (ull*)   (ws + 31456384);
    ull*    scanFlag= (ull*)   (ws + 31457408);

    prepF<<<PB, 256, 0, stream>>>(ei, ew, sd32, blockcnt, x, W1, xw1b,
                                  base8, cnt_arr, dinv, W2, w2pg, epack,
                                  histFlag, scanFlag);
    aggC<<<2500, 256, 0, stream>>>(xw1b, epack, cnt_arr, dinv, b1, w2pg, xw2b);
    agg2<<<2500, 256, 0, stream>>>(xw2b, epack, cnt_arr, dinv, b2, out);
}

// Round 12
// 138.385 us; speedup vs baseline: 1.5191x; 1.5191x over previous
//
#include <hip/hip_runtime.h>
#include <math.h>

#define N_NODES 10000
#define N_EDGES 640000
#define ELLW    192     // max in-degree slots; Poisson(64) max ~110, P[>192]~1e-19

#define CHUNKS  128
#define CHUNK_E 5000    // N_EDGES / CHUNKS exactly
#define GB      625     // ceil(10000/16) gemm1 tiles (TM=16)

typedef unsigned long long ull;
typedef unsigned int uint;
typedef unsigned short ushort;
typedef unsigned char uchar;

#define FIXED_SCALE 262144.0f   // 2^18; count<<24 | fixed18(sum_w); max cnt<64 -> no carry

// ---------------- workspace layout (bytes) ----------------
// xw1b     : N*128 bf16   @ 0            (2,560,000)
// xw2b     : N*64  bf16   @  5,120,000   (1,280,000)
// epack    : N*ELLW ull   @  6,400,000   (15,360,000)  (nrm_bits<<32 | src)
// blockcnt : CHUNKS*N u32 @ 21,760,000   (5,120,000)   [also epack-overshoot landing zone]
// base8    : CHUNKS*N u8  @ 26,880,000   (1,280,000)
// sd32     : E u32        @ 28,800,000   (2,560,000)   (rank4|dst14|src14)
// cnt_arr  : N int        @ 31,360,000   (40,000)
// dinv     : N f32        @ 31,400,000   (40,000)
// w2pg     : 4096 u32     @ 31,440,000   (16,384)      W2 packed bf16x2, once

__device__ __forceinline__ float bf_lo(uint u) { return __uint_as_float(u << 16); }
__device__ __forceinline__ float bf_hi(uint u) { return __uint_as_float(u & 0xffff0000u); }
__device__ __forceinline__ ushort f2bf(float v) {
    uint u = __float_as_uint(v);
    uint r = u + 0x7fffu + ((u >> 16) & 1u);   // round-to-nearest-even
    return (ushort)(r >> 16);
}

// 8 FMAs: one edge's 4 packed uints (8 bf16 cols) into acc[0..7]
#define ACC8(n, r) \
    acc[0] = fmaf(n, bf_lo((r).x), acc[0]); acc[1] = fmaf(n, bf_hi((r).x), acc[1]); \
    acc[2] = fmaf(n, bf_lo((r).y), acc[2]); acc[3] = fmaf(n, bf_hi((r).y), acc[3]); \
    acc[4] = fmaf(n, bf_lo((r).z), acc[4]); acc[5] = fmaf(n, bf_hi((r).z), acc[5]); \
    acc[6] = fmaf(n, bf_lo((r).w), acc[6]); acc[7] = fmaf(n, bf_hi((r).w), acc[7]);

// ====== kernel A: chunk histograms (128 blocks) + gemm1 (625 x TM=16 tiles) ======
__global__ __launch_bounds__(256) void kernelA(const int* __restrict__ ei,
                                               const float* __restrict__ ew,
                                               uint* __restrict__ sd32,
                                               uint* __restrict__ blockcnt,
                                               const float* __restrict__ x,
                                               const float* __restrict__ W1,
                                               ushort* __restrict__ xw1b) {
    __shared__ __align__(16) uint smem[N_NODES];   // 40 KB; gemm blocks overlay sA/sB here
    const int tid = threadIdx.x;
    if (blockIdx.x < CHUNKS) {
        const int c = blockIdx.x;
        __shared__ int sflag;
        if (tid == 0) sflag = 0;
        for (int i = tid; i < N_NODES; i += 256) smem[i] = 0u;
        __syncthreads();
        // layout self-detect: int64 LE [2,E] => sampled high dwords all zero;
        // int32 => random node ids (P[all 64 zero] ~ 1e-256)
        int a = (tid < 64) ? ei[2 * (c * CHUNK_E + tid) + 1] : 0;
        if (a) atomicOr(&sflag, 1);
        __syncthreads();
        const int f = sflag;                     // 1 => int32 layout
        const ull* ei64 = (const ull*)ei;
        for (int k = tid; k < CHUNK_E; k += 256) {
            int e = c * CHUNK_E + k;
            int s, d;
            if (f) { s = ei[e];        d = ei[N_EDGES + e]; }
            else   { s = (int)ei64[e]; d = (int)ei64[N_EDGES + e]; }
            float w = ew[e];
            uint fx = (uint)(w * FIXED_SCALE + 0.5f);
            uint old = atomicAdd(&smem[d], (1u << 24) | fx);
            uint r = (old >> 24) & 15u;          // per-chunk rank; fits 4 bits
            sd32[e] = (r << 28) | ((uint)d << 14) | (uint)s;
        }
        __syncthreads();
        for (int i = tid; i < N_NODES; i += 256)
            blockcnt[c * N_NODES + i] = smem[i];
    } else {
        // gemm1: xw1b[16-row tile] = x @ W1 (f32 acc -> bf16)
        // sA padded to LDA=36 floats: wave-uniform ds_read_b128 broadcast.
        constexpr int K = 128, TM = 16, KT = 32, NCOL = 128, RPT = 8, LDA = KT + 4;
        float* sA = (float*)smem;           // [16][36]
        float* sB = sA + TM * LDA;          // [32][128]
        int blk = blockIdx.x - CHUNKS;
        int c = tid % NCOL, rr = tid / NCOL;      // rr in [0,2)
        int row0 = blk * TM;
        float acc[RPT];
#pragma unroll
        for (int r = 0; r < RPT; ++r) acc[r] = 0.0f;
        for (int k0 = 0; k0 < K; k0 += KT) {
            for (int i = tid; i < TM * KT; i += 256) {
                int r = i / KT, k = i % KT;
                int gr = row0 + r;
                sA[r * LDA + k] = (gr < N_NODES) ? x[gr * K + k0 + k] : 0.0f;
            }
            for (int i = tid; i < KT * NCOL; i += 256) {
                int k = i / NCOL, cc = i % NCOL;
                sB[k * NCOL + cc] = W1[(k0 + k) * NCOL + cc];
            }
            __syncthreads();
#pragma unroll
            for (int k = 0; k < KT; k += 4) {
                float b0 = sB[(k + 0) * NCOL + c];
                float b1 = sB[(k + 1) * NCOL + c];
                float b2 = sB[(k + 2) * NCOL + c];
                float b3 = sB[(k + 3) * NCOL + c];
#pragma unroll
                for (int r = 0; r < RPT; ++r) {
                    const float4 av = *(const float4*)&sA[(rr * RPT + r) * LDA + k];
                    acc[r] = fmaf(av.x, b0, acc[r]);
                    acc[r] = fmaf(av.y, b1, acc[r]);
                    acc[r] = fmaf(av.z, b2, acc[r]);
                    acc[r] = fmaf(av.w, b3, acc[r]);
                }
            }
            __syncthreads();
        }
#pragma unroll
        for (int r = 0; r < RPT; ++r) {
            int gr = row0 + rr * RPT + r;
            if (gr < N_NODES) xw1b[gr * NCOL + c] = f2bf(acc[r]);
        }
    }
}

// ====== kernel B: per-node scan (blocks 0..39) + W2 bf16x2 pre-pack (40..55) ======
__global__ __launch_bounds__(256) void scanB(const uint* __restrict__ blockcnt,
                                             uchar* __restrict__ base8,
                                             int* __restrict__ cnt_arr,
                                             float* __restrict__ dinv,
                                             const float* __restrict__ W2,
                                             uint* __restrict__ w2pg) {
    if (blockIdx.x >= 40) {
        // pack W2 once: w2pg[k2*64+c] = bf16(W2[2k2][c]) | bf16(W2[2k2+1][c])<<16
        int i = (blockIdx.x - 40) * 256 + threadIdx.x;   // 16*256 = 4096 entries
        int k2 = i >> 6, cc = i & 63;
        uint lo = (uint)f2bf(W2[(2 * k2) * 64 + cc]);
        uint hi = (uint)f2bf(W2[(2 * k2 + 1) * 64 + cc]);
        w2pg[i] = lo | (hi << 16);
        return;
    }
    int n = blockIdx.x * 256 + threadIdx.x;
    if (n >= N_NODES) return;
    uint wsum = 0;
    int run = 0;
#pragma unroll 8
    for (int c = 0; c < CHUNKS; ++c) {
        uint v = blockcnt[c * N_NODES + n];
        base8[c * N_NODES + n] = (uchar)run;
        run += (int)(v >> 24);
        wsum += v & 0xffffffu;
    }
    cnt_arr[n] = run;
    float dg = 1.0f + (float)wsum * (1.0f / FIXED_SCALE);
    dinv[n] = (float)(1.0 / sqrt((double)dg));
}

// =============== kernel C: atomic-free ELL fill (2500 blocks: 1 edge/thread) ===============
__global__ __launch_bounds__(256) void fillC(const uint* __restrict__ sd32,
                                             const float* __restrict__ ew,
                                             const uchar* __restrict__ base8,
                                             const float* __restrict__ dinv,
                                             ull* __restrict__ epack) {
    const int gid = blockIdx.x * 256 + threadIdx.x;
    const int stride = gridDim.x * 256;
    for (int e = gid; e < N_EDGES; e += stride) {
        uint sd = sd32[e];
        int s = (int)(sd & 0x3fffu);
        int d = (int)((sd >> 14) & 0x3fffu);
        int r = (int)(sd >> 28);
        int c = e / CHUNK_E;
        float nrm = dinv[s] * ew[e] * dinv[d];
        int slot = (int)base8[c * N_NODES + d] + r;
        if (slot < ELLW)
            epack[d * ELLW + slot] = ((ull)__float_as_uint(nrm) << 32) | (ull)(uint)s;
    }
}

// ===== aggC: 2500 blocks x 256, wave per node, QUAD-GATHER layout (R7-proven).
// Wave = 4 row-groups x 16 lanes; one dwordx4 gather covers 4 edges (1 KB).
// Per-iter issue ~200 cyc roughly covers the 1-deep meta prefetch distance. =====
__global__ __launch_bounds__(256, 6) void aggC(const ushort* __restrict__ xw1b,
                                               const ull* __restrict__ epack,
                                               const int* __restrict__ cnt_arr,
                                               const float* __restrict__ dinv,
                                               const float* __restrict__ b1,
                                               const uint* __restrict__ w2pg,
                                               ushort* __restrict__ xw2b) {
    __shared__ float hl[4][128];        // 2 KB f32 h rows
    __shared__ uint w2p[64 * 64];       // 16 KB packed bf16x2 W2
    const uint* __restrict__ xw32 = (const uint*)xw1b;   // row = 64 uints
    const int tid = threadIdx.x;
    const int l = tid & 63;
    const int wv = tid >> 6;
    const int g = l >> 4;               // row-group 0..3
    const int q = l & 15;               // covers cols 8q..8q+7 (uints 4q..4q+3)
    const int node = blockIdx.x * 4 + wv;

    int cnt = __builtin_amdgcn_readfirstlane(cnt_arr[node]);
    if (cnt > ELLW) cnt = ELLW;
    const ull* ep = epack + (long)node * ELLW;

    // prologue: edge meta for batch 0 (latency hides under w2p staging)
    ulonglong2 eA = *(const ulonglong2*)(ep + 2 * g);        // edges 2g, 2g+1
    ulonglong2 eB = *(const ulonglong2*)(ep + 8 + 2 * g);    // edges 8+2g, 9+2g

    for (int i = tid; i < 64 * 64; i += 256) w2p[i] = w2pg[i];

    float acc[8];
#pragma unroll
    for (int i = 0; i < 8; ++i) acc[i] = 0.0f;

    for (int j = 0; j < cnt; j += 16) {
        // prefetch next batch's meta (OOB overshoot lands in blockcnt region)
        ulonglong2 nA = *(const ulonglong2*)(ep + j + 16 + 2 * g);
        ulonglong2 nB = *(const ulonglong2*)(ep + j + 24 + 2 * g);
        uint s0 = (uint)eA.x & 0x3fffu;
        uint s1 = (uint)eA.y & 0x3fffu;
        uint s2 = (uint)eB.x & 0x3fffu;
        uint s3 = (uint)eB.y & 0x3fffu;
        uint4 r0 = *(const uint4*)(xw32 + s0 * 64 + q * 4);
        uint4 r1 = *(const uint4*)(xw32 + s1 * 64 + q * 4);
        uint4 r2 = *(const uint4*)(xw32 + s2 * 64 + q * 4);
        uint4 r3 = *(const uint4*)(xw32 + s3 * 64 + q * 4);
        float n0 = (j + 2 * g     < cnt) ? __uint_as_float((uint)(eA.x >> 32)) : 0.0f;
        float n1 = (j + 2 * g + 1 < cnt) ? __uint_as_float((uint)(eA.y >> 32)) : 0.0f;
        float n2 = (j + 2 * g + 8 < cnt) ? __uint_as_float((uint)(eB.x >> 32)) : 0.0f;
        float n3 = (j + 2 * g + 9 < cnt) ? __uint_as_float((uint)(eB.y >> 32)) : 0.0f;
        ACC8(n0, r0)
        ACC8(n1, r1)
        ACC8(n2, r2)
        ACC8(n3, r3)
        eA = nA; eB = nB;
    }

    // merge the 4 row-groups' partials
#pragma unroll
    for (int i = 0; i < 8; ++i) {
        acc[i] += __shfl_xor(acc[i], 16, 64);
        acc[i] += __shfl_xor(acc[i], 32, 64);
    }

    float dn = dinv[node];
    float d2 = dn * dn;
    uint4 sv = *(const uint4*)(xw32 + node * 64 + q * 4);    // self row slice
    float4 b1a = *(const float4*)(b1 + 8 * q);
    float4 b1b = *(const float4*)(b1 + 8 * q + 4);
    if (g == 0) {
        hl[wv][8 * q + 0] = fmaxf(acc[0] + d2 * bf_lo(sv.x) + b1a.x, 0.0f);
        hl[wv][8 * q + 1] = fmaxf(acc[1] + d2 * bf_hi(sv.x) + b1a.y, 0.0f);
        hl[wv][8 * q + 2] = fmaxf(acc[2] + d2 * bf_lo(sv.y) + b1a.z, 0.0f);
        hl[wv][8 * q + 3] = fmaxf(acc[3] + d2 * bf_hi(sv.y) + b1a.w, 0.0f);
        hl[wv][8 * q + 4] = fmaxf(acc[4] + d2 * bf_lo(sv.z) + b1b.x, 0.0f);
        hl[wv][8 * q + 5] = fmaxf(acc[5] + d2 * bf_hi(sv.z) + b1b.y, 0.0f);
        hl[wv][8 * q + 6] = fmaxf(acc[6] + d2 * bf_lo(sv.w) + b1b.z, 0.0f);
        hl[wv][8 * q + 7] = fmaxf(acc[7] + d2 * bf_hi(sv.w) + b1b.w, 0.0f);
    }
    __syncthreads();

    // mini-gemm: thread (wv,l) -> node, column l. hl broadcast reads; one
    // ds_read_b32 per two k's from packed bf16 W2.
    float acc2 = 0.0f;
#pragma unroll 8
    for (int k2 = 0; k2 < 64; ++k2) {
        uint w = w2p[k2 * 64 + l];
        acc2 = fmaf(hl[wv][2 * k2],     bf_lo(w), acc2);
        acc2 = fmaf(hl[wv][2 * k2 + 1], bf_hi(w), acc2);
    }
    xw2b[node * 64 + l] = f2bf(acc2);
}

// ===== agg2: 2500 blocks x 256, wave per node, quad-gather, 2-DEEP prefetch.
// Per-iter issue ~80 cyc < L2 latency 200-400 cyc: 1-deep left a partial
// stall; holding eA (iter j) + eB (iter j+16) and prefetching j+32 doubles
// the cover at +2 VGPR (well inside (256,8) cap). No LDS. =====
__global__ __launch_bounds__(256, 8) void agg2(const ushort* __restrict__ xw2b,
                                               const ull* __restrict__ epack,
                                               const int* __restrict__ cnt_arr,
                                               const float* __restrict__ dinv,
                                               const float* __restrict__ b2,
                                               float* __restrict__ out) {
    const uint* __restrict__ xw32 = (const uint*)xw2b;   // row = 32 uints
    const int tid = threadIdx.x;
    const int l = tid & 63;
    const int wv = tid >> 6;
    const int g = l >> 3;               // row-group 0..7
    const int q = l & 7;                // covers cols 8q..8q+7 (uints 4q..4q+3)
    const int node = blockIdx.x * 4 + wv;

    int cnt = __builtin_amdgcn_readfirstlane(cnt_arr[node]);
    if (cnt > ELLW) cnt = ELLW;
    const ull* ep = epack + (long)node * ELLW;

    ulonglong2 eA = *(const ulonglong2*)(ep + 2 * g);        // iter j=0 meta
    ulonglong2 eB = *(const ulonglong2*)(ep + 16 + 2 * g);   // iter j=16 meta

    float acc[8];
#pragma unroll
    for (int i = 0; i < 8; ++i) acc[i] = 0.0f;

    for (int j = 0; j < cnt; j += 16) {
        // prefetch iter j+32's meta (2-deep; OOB overshoot stays in workspace)
        ulonglong2 nA = *(const ulonglong2*)(ep + j + 32 + 2 * g);
        uint s0 = (uint)eA.x & 0x3fffu;
        uint s1 = (uint)eA.y & 0x3fffu;
        uint4 r0 = *(const uint4*)(xw32 + s0 * 32 + q * 4);
        uint4 r1 = *(const uint4*)(xw32 + s1 * 32 + q * 4);
        float n0 = (j + 2 * g     < cnt) ? __uint_as_float((uint)(eA.x >> 32)) : 0.0f;
        float n1 = (j + 2 * g + 1 < cnt) ? __uint_as_float((uint)(eA.y >> 32)) : 0.0f;
        ACC8(n0, r0)
        ACC8(n1, r1)
        eA = eB; eB = nA;
    }

#pragma unroll
    for (int i = 0; i < 8; ++i) {
        acc[i] += __shfl_xor(acc[i], 8, 64);
        acc[i] += __shfl_xor(acc[i], 16, 64);
        acc[i] += __shfl_xor(acc[i], 32, 64);
    }

    float dn = dinv[node];
    float d2 = dn * dn;
    uint4 sv = *(const uint4*)(xw32 + node * 32 + q * 4);    // self row slice
    float4 b2a = *(const float4*)(b2 + 8 * q);
    float4 b2b = *(const float4*)(b2 + 8 * q + 4);
    if (g == 0) {
        float4 oa, ob;
        oa.x = acc[0] + d2 * bf_lo(sv.x) + b2a.x;
        oa.y = acc[1] + d2 * bf_hi(sv.x) + b2a.y;
        oa.z = acc[2] + d2 * bf_lo(sv.y) + b2a.z;
        oa.w = acc[3] + d2 * bf_hi(sv.y) + b2a.w;
        ob.x = acc[4] + d2 * bf_lo(sv.z) + b2b.x;
        ob.y = acc[5] + d2 * bf_hi(sv.z) + b2b.y;
        ob.z = acc[6] + d2 * bf_lo(sv.w) + b2b.z;
        ob.w = acc[7] + d2 * bf_hi(sv.w) + b2b.w;
        *(float4*)(out + node * 64 + 8 * q)     = oa;
        *(float4*)(out + node * 64 + 8 * q + 4) = ob;
    }
}

extern "C" void kernel_launch(void* const* d_in, const int* in_sizes, int n_in,
                              void* d_out, int out_size, void* d_ws, size_t ws_size,
                              hipStream_t stream) {
    const float* x  = (const float*)d_in[0];
    const int*   ei = (const int*)d_in[1];
    const float* ew = (const float*)d_in[2];
    const float* W1 = (const float*)d_in[3];
    const float* b1 = (const float*)d_in[4];
    const float* W2 = (const float*)d_in[5];
    const float* b2 = (const float*)d_in[6];
    float* out = (float*)d_out;

    char* ws = (char*)d_ws;
    ushort* xw1b    = (ushort*)(ws + 0);
    ushort* xw2b    = (ushort*)(ws + 5120000);
    ull*    epack   = (ull*)   (ws + 6400000);
    uint*   blockcnt= (uint*)  (ws + 21760000);
    uchar*  base8   = (uchar*) (ws + 26880000);
    uint*   sd32    = (uint*)  (ws + 28800000);
    int*    cnt_arr = (int*)   (ws + 31360000);
    float*  dinv    = (float*) (ws + 31400000);
    uint*   w2pg    = (uint*)  (ws + 31440000);

    kernelA<<<CHUNKS + GB, 256, 0, stream>>>(ei, ew, sd32, blockcnt, x, W1, xw1b);
    scanB<<<56, 256, 0, stream>>>(blockcnt, base8, cnt_arr, dinv, W2, w2pg);
    fillC<<<2500, 256, 0, stream>>>(sd32, ew, base8, dinv, epack);
    aggC<<<2500, 256, 0, stream>>>(xw1b, epack, cnt_arr, dinv, b1, w2pg, xw2b);
    agg2<<<2500, 256, 0, stream>>>(xw2b, epack, cnt_arr, dinv, b2, out);
}